// Round 5
// baseline (194.879 us; speedup 1.0000x reference)
//
#include <hip/hip_runtime.h>

// Attention B=2,H=16,S=2048,D=64 fp32. Round 5: barrier-free f16 MFMA FA,
// double-tile K=32 PV, ping-pong prefetch, LDS-free prep.
//
// prep: K -> f16 with scale*log2e folded (main loop = raw exp2); V -> f16
// transposed Vt[bh][d][s] via per-thread 4x4 in-register transpose (no LDS;
// every global instr fully covers its cachelines).
//
// fa5: grid 1024 = (bh 32)x(qt 32), 256 thr. Wave w owns keys {16w+0..15} of
// every tile; accumulates partial O (64 qrows x 64 d) over its keys. ZERO
// barriers in the K-loop:
//   S^T = mfma_16x16x32(A=K,B=Q) C-layout (qrow=lane&15, key=4*quad+r)
//   feeds PV directly as A-operand. Two consecutive tiles' P fragments
//   concatenate lane-locally into the K=32 A-layout (k=8*quad+j: j<4 ->
//   tile0 key 4*quad+j, j>=4 -> tile1 key 4*quad+j-4); V fragments use the
//   SAME k ordering (two 8B Vt loads per dt) -> PV is 16 x 16x16x32 mfmas
//   per double-tile (was 32 x K=16 equivalents). Ping-pong A/B register
//   buffers: loads for DT i+1 issue before compute of DT i, no copies.
// Epilogue: 2-buffer LDS tree reduction of the 4 partial O's + row sums.
// XCD-affine: blockIdx%8 == bh%8 -> each bh's 1MB kh+vt slab L2-resident.

typedef _Float16 f16;
typedef __attribute__((ext_vector_type(8))) _Float16 f16x8;
typedef __attribute__((ext_vector_type(4))) _Float16 f16x4;
typedef __attribute__((ext_vector_type(4))) float f32x4;

constexpr int Bc = 2, Hc = 16, Sc = 2048, Dc = 64;
constexpr size_t NE = (size_t)Bc * Hc * Sc * Dc;

// ---------------- prep: K*scale -> f16; V -> f16 transposed (no LDS) ------
__global__ __launch_bounds__(256)
void prep(const float* __restrict__ kp, const float* __restrict__ vp,
          const float* __restrict__ temp,
          f16* __restrict__ kh, f16* __restrict__ vt) {
  const int tid = threadIdx.x;
  const int bh = blockIdx.x & 31;
  const int st = blockIdx.x >> 5;            // 64-row s-tile, 0..31
  const float ksc = 1.44269504088896340736f / (temp[0] * 8.0f);

  const size_t base = (size_t)bh * Sc * Dc + (size_t)st * 64 * Dc;
  const float* kg = kp + base;
  f16* khg = kh + base;
#pragma unroll
  for (int i = 0; i < 4; ++i) {
    int f = tid + (i << 8);
    f32x4 a = *(const f32x4*)(kg + f * 4);
    *(f16x4*)(khg + f * 4) = (f16x4){(f16)(a.x * ksc), (f16)(a.y * ksc),
                                     (f16)(a.z * ksc), (f16)(a.w * ksc)};
  }

  // V 4x4 in-register transpose: thread (sb=tid&15, db=tid>>4)
  const int sb = tid & 15, db = tid >> 4;
  const float* vg = vp + base;
  f32x4 r0 = *(const f32x4*)(vg + (4 * sb + 0) * Dc + 4 * db);
  f32x4 r1 = *(const f32x4*)(vg + (4 * sb + 1) * Dc + 4 * db);
  f32x4 r2 = *(const f32x4*)(vg + (4 * sb + 2) * Dc + 4 * db);
  f32x4 r3 = *(const f32x4*)(vg + (4 * sb + 3) * Dc + 4 * db);
  f16* vtg = vt + (size_t)bh * Dc * Sc + (size_t)st * 64 + 4 * sb;
  *(f16x4*)(vtg + (size_t)(4 * db + 0) * Sc) = (f16x4){(f16)r0.x, (f16)r1.x, (f16)r2.x, (f16)r3.x};
  *(f16x4*)(vtg + (size_t)(4 * db + 1) * Sc) = (f16x4){(f16)r0.y, (f16)r1.y, (f16)r2.y, (f16)r3.y};
  *(f16x4*)(vtg + (size_t)(4 * db + 2) * Sc) = (f16x4){(f16)r0.z, (f16)r1.z, (f16)r2.z, (f16)r3.z};
  *(f16x4*)(vtg + (size_t)(4 * db + 3) * Sc) = (f16x4){(f16)r0.w, (f16)r1.w, (f16)r2.w, (f16)r3.w};
}

// ---------------- fa5: barrier-free double-tile flash attention -----------
__global__ __launch_bounds__(256, 2)
void fa5(const float* __restrict__ qp, const f16* __restrict__ kh,
         const f16* __restrict__ vt, float* __restrict__ out) {
  __shared__ float OsA[64][66];
  __shared__ float OsB[64][66];
  __shared__ float Lred[4][64];

  const int tid = threadIdx.x, lane = tid & 63, w = tid >> 6;
  const int lq = lane & 15, qd = lane >> 4;
  const int L = blockIdx.x;
  const int bh = L & 31;                     // blockIdx%8 == bh%8
  const int qt = L >> 5;

  const size_t base = (size_t)bh * Sc * Dc;
  const float* qg = qp + base + (size_t)qt * 64 * Dc;
  const f16* kg = kh + base + (size_t)(16 * w + lq) * Dc + 8 * qd;
  const f16* vg = vt + (size_t)bh * Dc * Sc + 16 * w + 4 * qd;

  // ---- Q B-fragments (persistent) ----
  f16x8 Qf[4][2];
#pragma unroll
  for (int nt = 0; nt < 4; ++nt)
#pragma unroll
    for (int kc = 0; kc < 2; ++kc) {
      const float* p = qg + (16 * nt + lq) * Dc + 32 * kc + 8 * qd;
      f32x4 a = *(const f32x4*)p;
      f32x4 b = *(const f32x4*)(p + 4);
      Qf[nt][kc] = (f16x8){(f16)a.x, (f16)a.y, (f16)a.z, (f16)a.w,
                           (f16)b.x, (f16)b.y, (f16)b.z, (f16)b.w};
    }

  f32x4 Oa[4][4];
  float ls[4];
#pragma unroll
  for (int nt = 0; nt < 4; ++nt) {
    ls[nt] = 0.f;
#pragma unroll
    for (int dt = 0; dt < 4; ++dt) Oa[nt][dt] = (f32x4){0.f, 0.f, 0.f, 0.f};
  }

  // load double-tile d (tiles 2d, 2d+1): 4x16B K + 8x8B V
  auto loadDT = [&](int d, f16x8* K, f16x8* V) {
    const f16* pk = kg + (size_t)d * 128 * Dc;
    K[0] = *(const f16x8*)(pk);
    K[1] = *(const f16x8*)(pk + 32);
    K[2] = *(const f16x8*)(pk + 64 * Dc);
    K[3] = *(const f16x8*)(pk + 64 * Dc + 32);
    const f16* pv = vg + d * 128;
#pragma unroll
    for (int dt = 0; dt < 4; ++dt) {
      const f16* r = pv + (size_t)(16 * dt + lq) * Sc;
      *(f16x4*)&V[dt] = *(const f16x4*)(r);            // tile0 keys
      *((f16x4*)&V[dt] + 1) = *(const f16x4*)(r + 64); // tile1 keys
    }
  };

  auto computeDT = [&](const f16x8* K, const f16x8* V) {
    f32x4 Se[4], So[4];
#pragma unroll
    for (int nt = 0; nt < 4; ++nt) {
      f32x4 a = (f32x4){0.f, 0.f, 0.f, 0.f};
      a = __builtin_amdgcn_mfma_f32_16x16x32_f16(K[0], Qf[nt][0], a, 0, 0, 0);
      a = __builtin_amdgcn_mfma_f32_16x16x32_f16(K[1], Qf[nt][1], a, 0, 0, 0);
      Se[nt] = a;
      f32x4 b = (f32x4){0.f, 0.f, 0.f, 0.f};
      b = __builtin_amdgcn_mfma_f32_16x16x32_f16(K[2], Qf[nt][0], b, 0, 0, 0);
      b = __builtin_amdgcn_mfma_f32_16x16x32_f16(K[3], Qf[nt][1], b, 0, 0, 0);
      So[nt] = b;
    }
    f16x8 PP[4];
#pragma unroll
    for (int nt = 0; nt < 4; ++nt) {
      float e0 = exp2f(Se[nt].x), e1 = exp2f(Se[nt].y);
      float e2 = exp2f(Se[nt].z), e3 = exp2f(Se[nt].w);
      float o0 = exp2f(So[nt].x), o1 = exp2f(So[nt].y);
      float o2 = exp2f(So[nt].z), o3 = exp2f(So[nt].w);
      ls[nt] += ((e0 + e1) + (e2 + e3)) + ((o0 + o1) + (o2 + o3));
      PP[nt] = (f16x8){(f16)e0, (f16)e1, (f16)e2, (f16)e3,
                       (f16)o0, (f16)o1, (f16)o2, (f16)o3};
    }
#pragma unroll
    for (int nt = 0; nt < 4; ++nt)
#pragma unroll
      for (int dt = 0; dt < 4; ++dt)
        Oa[nt][dt] =
            __builtin_amdgcn_mfma_f32_16x16x32_f16(PP[nt], V[dt], Oa[nt][dt], 0, 0, 0);
  };

  f16x8 KA[4], VA[4], KB[4], VB[4];
  loadDT(0, KA, VA);
#pragma unroll 1
  for (int i = 0; i < 16; i += 2) {
    loadDT(i + 1, KB, VB);
    computeDT(KA, VA);
    loadDT(i + 2 < 16 ? i + 2 : 15, KA, VA);
    computeDT(KB, VB);
  }

  // ---- row-sum partials ----
#pragma unroll
  for (int nt = 0; nt < 4; ++nt) {
    float l = ls[nt];
    l += __shfl_xor(l, 16, 64);
    l += __shfl_xor(l, 32, 64);
    if (qd == 0) Lred[w][16 * nt + lq] = l;
  }

  // ---- pairwise tree reduction of partial O ----
  float(&Os)[64][66] = (w & 2) ? OsB : OsA;
  if (!(w & 1)) {
#pragma unroll
    for (int nt = 0; nt < 4; ++nt)
#pragma unroll
      for (int dt = 0; dt < 4; ++dt)
#pragma unroll
        for (int r = 0; r < 4; ++r)
          Os[16 * nt + 4 * qd + r][16 * dt + lq] = Oa[nt][dt][r];
  }
  __syncthreads();
  if (w & 1) {
#pragma unroll
    for (int nt = 0; nt < 4; ++nt)
#pragma unroll
      for (int dt = 0; dt < 4; ++dt)
#pragma unroll
        for (int r = 0; r < 4; ++r)
          Os[16 * nt + 4 * qd + r][16 * dt + lq] += Oa[nt][dt][r];
  }
  __syncthreads();

  // ---- final: out = (OsA+OsB)/l ----
  float* og = out + base + (size_t)qt * 64 * Dc;
#pragma unroll
  for (int r = 0; r < 16; ++r) {
    int row = 16 * w + r;
    float l = Lred[0][row] + Lred[1][row] + Lred[2][row] + Lred[3][row];
    float vo = OsA[row][lane] + OsB[row][lane];
    og[(size_t)row * Dc + lane] = vo / l;
  }
}

extern "C" void kernel_launch(void* const* d_in, const int* in_sizes, int n_in,
                              void* d_out, int out_size, void* d_ws, size_t ws_size,
                              hipStream_t stream) {
  const float* q    = (const float*)d_in[0];
  const float* k    = (const float*)d_in[1];
  const float* v    = (const float*)d_in[2];
  const float* temp = (const float*)d_in[3];
  float* out = (float*)d_out;

  f16* kh = (f16*)d_ws;          // 8.4 MB
  f16* vt = kh + NE;             // 8.4 MB

  dim3 block(256);
  prep<<<dim3(Bc * Hc * (Sc / 64)), block, 0, stream>>>(k, v, temp, kh, vt);
  fa5<<<dim3(Bc * Hc * (Sc / 64)), block, 0, stream>>>(q, kh, vt, out);
}

// Round 6
// 189.167 us; speedup vs baseline: 1.0302x; 1.0302x over previous
//
#include <hip/hip_runtime.h>

// Attention B=2,H=16,S=2048,D=64 fp32. Round 6: barrier-free f16 MFMA FA,
// VALU diet + 3 waves/SIMD.
//
// Diagnosis from r3-r5 (all ~110-130us): MFMA pipe does exactly the floor
// work (MfmaUtil*dur ~= 14us every round); VALUBusy*dur ~= 36us (2x the MFMA
// stream: elementwise cvts + 64-bit addr recompute); rest = unhidden load
// latency at 2 waves/SIMD. Fixes:
//  - packed f32->f16 via __builtin_amdgcn_cvt_pkrtz (was 8 cvt+pack per x8)
//  - all global addresses = loop-invariant pointers bumped by constants
//  - single-tile loop, K ping-ponged one tile ahead (no reg copies), V
//    loaded at iter top (used ~400cyc later, covers L2)
//  - register budget ~170 unified (Qf 32 + Oa 64 AGPR + K 16 + V 8 + misc)
//    -> 3 waves/SIMD, enforced by __launch_bounds__(256,3)
//
// Structure (unchanged, correctness-proven r4/r5): wave w owns keys
// {16w..16w+15} of every 64-key tile, accumulates partial O over all 64
// qrows x 64 d. S^T = mfma_16x16x32(A=K,B=Q) lands in C-layout
// (key=4*quad+r, qrow=lane&15) which IS the K=16 A-operand layout, so
// exp(S^T) feeds PV (O = P V via A=P, B=Vt) straight from registers.
// Zero barriers in the K-loop; 2-buffer LDS tree reduction at the end.
// prep folds scale*log2e into K (main loop = raw exp2) and transposes V.

typedef _Float16 f16;
typedef __attribute__((ext_vector_type(4))) _Float16 f16x4;
typedef __attribute__((ext_vector_type(8))) _Float16 f16x8;
typedef __attribute__((ext_vector_type(4))) float f32x4;

constexpr int Bc = 2, Hc = 16, Sc = 2048, Dc = 64;
constexpr size_t NE = (size_t)Bc * Hc * Sc * Dc;

// ---------------- prep: K*scale -> f16; V -> f16 transposed (no LDS) ------
__global__ __launch_bounds__(256)
void prep(const float* __restrict__ kp, const float* __restrict__ vp,
          const float* __restrict__ temp,
          f16* __restrict__ kh, f16* __restrict__ vt) {
  const int tid = threadIdx.x;
  const int bh = blockIdx.x & 31;
  const int st = blockIdx.x >> 5;            // 64-row s-tile, 0..31
  const float ksc = 1.44269504088896340736f / (temp[0] * 8.0f);

  const size_t base = (size_t)bh * Sc * Dc + (size_t)st * 64 * Dc;
  const float* kg = kp + base;
  f16* khg = kh + base;
#pragma unroll
  for (int i = 0; i < 4; ++i) {
    int f = tid + (i << 8);
    f32x4 a = *(const f32x4*)(kg + f * 4);
    *(f16x4*)(khg + f * 4) = (f16x4){(f16)(a.x * ksc), (f16)(a.y * ksc),
                                     (f16)(a.z * ksc), (f16)(a.w * ksc)};
  }

  // V 4x4 in-register transpose: thread (sb=tid&15, db=tid>>4)
  const int sb = tid & 15, db = tid >> 4;
  const float* vg = vp + base;
  f32x4 r0 = *(const f32x4*)(vg + (4 * sb + 0) * Dc + 4 * db);
  f32x4 r1 = *(const f32x4*)(vg + (4 * sb + 1) * Dc + 4 * db);
  f32x4 r2 = *(const f32x4*)(vg + (4 * sb + 2) * Dc + 4 * db);
  f32x4 r3 = *(const f32x4*)(vg + (4 * sb + 3) * Dc + 4 * db);
  f16* vtg = vt + (size_t)bh * Dc * Sc + (size_t)st * 64 + 4 * sb;
  *(f16x4*)(vtg + (size_t)(4 * db + 0) * Sc) = (f16x4){(f16)r0.x, (f16)r1.x, (f16)r2.x, (f16)r3.x};
  *(f16x4*)(vtg + (size_t)(4 * db + 1) * Sc) = (f16x4){(f16)r0.y, (f16)r1.y, (f16)r2.y, (f16)r3.y};
  *(f16x4*)(vtg + (size_t)(4 * db + 2) * Sc) = (f16x4){(f16)r0.z, (f16)r1.z, (f16)r2.z, (f16)r3.z};
  *(f16x4*)(vtg + (size_t)(4 * db + 3) * Sc) = (f16x4){(f16)r0.w, (f16)r1.w, (f16)r2.w, (f16)r3.w};
}

// ---------------- fa6: barrier-free flash attention, 3 waves/SIMD ---------
__global__ __launch_bounds__(256, 3)
void fa6(const float* __restrict__ qp, const f16* __restrict__ kh,
         const f16* __restrict__ vt, float* __restrict__ out) {
  __shared__ float OsA[64][66];
  __shared__ float OsB[64][66];
  __shared__ float Lred[4][64];

  const int tid = threadIdx.x, lane = tid & 63, w = tid >> 6;
  const int lq = lane & 15, qd = lane >> 4;
  const int L = blockIdx.x;
  const int bh = L & 31;                     // blockIdx%8 == bh%8 (XCD-affine)
  const int qt = L >> 5;

  const size_t base = (size_t)bh * Sc * Dc;
  const float* qg = qp + base + (size_t)qt * 64 * Dc;

  // ---- Q B-fragments (one-time cvt; packed) ----
  f16x8 Qf[4][2];
#pragma unroll
  for (int nt = 0; nt < 4; ++nt)
#pragma unroll
    for (int kc = 0; kc < 2; ++kc) {
      const float* p = qg + (16 * nt + lq) * Dc + 32 * kc + 8 * qd;
      f32x4 a = *(const f32x4*)p;
      f32x4 b = *(const f32x4*)(p + 4);
      auto p0 = __builtin_amdgcn_cvt_pkrtz(a.x, a.y);
      auto p1 = __builtin_amdgcn_cvt_pkrtz(a.z, a.w);
      auto p2 = __builtin_amdgcn_cvt_pkrtz(b.x, b.y);
      auto p3 = __builtin_amdgcn_cvt_pkrtz(b.z, b.w);
      f16x8 qf;
      ((decltype(p0)*)&qf)[0] = p0;
      ((decltype(p0)*)&qf)[1] = p1;
      ((decltype(p0)*)&qf)[2] = p2;
      ((decltype(p0)*)&qf)[3] = p3;
      Qf[nt][kc] = qf;
    }

  f32x4 Oa[4][4];
  float ls[4];
#pragma unroll
  for (int nt = 0; nt < 4; ++nt) {
    ls[nt] = 0.f;
#pragma unroll
    for (int dt = 0; dt < 4; ++dt) Oa[nt][dt] = (f32x4){0.f, 0.f, 0.f, 0.f};
  }

  // ---- loop-invariant lane-folded pointers, bumped by constants ----
  const f16* kptr = kh + base + (size_t)(16 * w + lq) * Dc + 8 * qd;
  const f16* vp0 = vt + (size_t)bh * Dc * Sc + (size_t)lq * Sc + 16 * w + 4 * qd;
  const f16* vp1 = vp0 + (size_t)16 * Sc;
  const f16* vp2 = vp0 + (size_t)32 * Sc;
  const f16* vp3 = vp0 + (size_t)48 * Sc;

  // one 64-key tile: QK (K=32) -> exp2 + packed cvt -> PV (K=16)
  auto tile = [&](const f16x8& K0, const f16x8& K1, const f16x4* V) {
    f32x4 St[4];
#pragma unroll
    for (int nt = 0; nt < 4; ++nt) {
      f32x4 a = (f32x4){0.f, 0.f, 0.f, 0.f};
      a = __builtin_amdgcn_mfma_f32_16x16x32_f16(K0, Qf[nt][0], a, 0, 0, 0);
      a = __builtin_amdgcn_mfma_f32_16x16x32_f16(K1, Qf[nt][1], a, 0, 0, 0);
      St[nt] = a;
    }
    f16x4 Pf[4];
#pragma unroll
    for (int nt = 0; nt < 4; ++nt) {
      float e0 = exp2f(St[nt].x), e1 = exp2f(St[nt].y);
      float e2 = exp2f(St[nt].z), e3 = exp2f(St[nt].w);
      ls[nt] += (e0 + e1) + (e2 + e3);
      auto lo = __builtin_amdgcn_cvt_pkrtz(e0, e1);
      auto hi = __builtin_amdgcn_cvt_pkrtz(e2, e3);
      f16x4 p;
      ((decltype(lo)*)&p)[0] = lo;
      ((decltype(lo)*)&p)[1] = hi;
      Pf[nt] = p;
    }
#pragma unroll
    for (int nt = 0; nt < 4; ++nt)
#pragma unroll
      for (int dt = 0; dt < 4; ++dt)
        Oa[nt][dt] = __builtin_amdgcn_mfma_f32_16x16x16f16(Pf[nt], V[dt],
                                                           Oa[nt][dt], 0, 0, 0);
  };

  f16x8 KA0 = *(const f16x8*)kptr;
  f16x8 KA1 = *(const f16x8*)(kptr + 32);

#pragma unroll 1
  for (int kt = 0; kt < 32; kt += 2) {
    // even tile: loads first (V for this tile, K for next), compute with KA
    f16x4 V[4] = {*(const f16x4*)vp0, *(const f16x4*)vp1,
                  *(const f16x4*)vp2, *(const f16x4*)vp3};
    const f16* kn = kptr + (size_t)64 * Dc;
    f16x8 KB0 = *(const f16x8*)kn;
    f16x8 KB1 = *(const f16x8*)(kn + 32);
    vp0 += 64; vp1 += 64; vp2 += 64; vp3 += 64;
    tile(KA0, KA1, V);

    // odd tile: compute with KB, prefetch KA (guarded on last)
    f16x4 W[4] = {*(const f16x4*)vp0, *(const f16x4*)vp1,
                  *(const f16x4*)vp2, *(const f16x4*)vp3};
    const f16* kn2 = (kt + 2 < 32) ? kn + (size_t)64 * Dc : kn;
    KA0 = *(const f16x8*)kn2;
    KA1 = *(const f16x8*)(kn2 + 32);
    kptr = kn2;
    vp0 += 64; vp1 += 64; vp2 += 64; vp3 += 64;
    tile(KB0, KB1, W);
  }

  // ---- row-sum partials: cross-quad shuffle, publish per wave ----
#pragma unroll
  for (int nt = 0; nt < 4; ++nt) {
    float l = ls[nt];
    l += __shfl_xor(l, 16, 64);
    l += __shfl_xor(l, 32, 64);
    if (qd == 0) Lred[w][16 * nt + lq] = l;
  }

  // ---- pairwise tree reduction of partial O through LDS ----
  float(&Os)[64][66] = (w & 2) ? OsB : OsA;
  if (!(w & 1)) {
#pragma unroll
    for (int nt = 0; nt < 4; ++nt)
#pragma unroll
      for (int dt = 0; dt < 4; ++dt)
#pragma unroll
        for (int r = 0; r < 4; ++r)
          Os[16 * nt + 4 * qd + r][16 * dt + lq] = Oa[nt][dt][r];
  }
  __syncthreads();
  if (w & 1) {
#pragma unroll
    for (int nt = 0; nt < 4; ++nt)
#pragma unroll
      for (int dt = 0; dt < 4; ++dt)
#pragma unroll
        for (int r = 0; r < 4; ++r)
          Os[16 * nt + 4 * qd + r][16 * dt + lq] += Oa[nt][dt][r];
  }
  __syncthreads();

  // ---- final: out = (OsA+OsB)/l ----
  float* og = out + base + (size_t)qt * 64 * Dc;
#pragma unroll
  for (int r = 0; r < 16; ++r) {
    int row = 16 * w + r;
    float l = Lred[0][row] + Lred[1][row] + Lred[2][row] + Lred[3][row];
    float vo = OsA[row][lane] + OsB[row][lane];
    og[(size_t)row * Dc + lane] = vo / l;
  }
}

extern "C" void kernel_launch(void* const* d_in, const int* in_sizes, int n_in,
                              void* d_out, int out_size, void* d_ws, size_t ws_size,
                              hipStream_t stream) {
  const float* q    = (const float*)d_in[0];
  const float* k    = (const float*)d_in[1];
  const float* v    = (const float*)d_in[2];
  const float* temp = (const float*)d_in[3];
  float* out = (float*)d_out;

  f16* kh = (f16*)d_ws;          // 8.4 MB
  f16* vt = kh + NE;             // 8.4 MB

  dim3 block(256);
  prep<<<dim3(Bc * Hc * (Sc / 64)), block, 0, stream>>>(k, v, temp, kh, vt);
  fa6<<<dim3(Bc * Hc * (Sc / 64)), block, 0, stream>>>(q, kh, vt, out);
}